// Round 3
// baseline (225.387 us; speedup 1.0000x reference)
//
#include <hip/hip_runtime.h>
#include <stdint.h>

// Linformer attention, MI355X gfx950 — 4-dispatch pipeline.
//   K1: KV = [Wk;Wv] @ I[b]^T          [4][512][8192] bf16 (XCD-swizzled for I L2 reuse)
//   K2: {KeT,VfT} split-K partials      [8][16][65536] f32 (fused k/v halves)
//   K3: reduce 16 partials -> bf16      [8][65536]
//   K4: flash2: Q = I@Wq^T (in-block) -> S = Q@KeT^T -> softmax -> Head = P@VfT^T -> f32 out

typedef unsigned short u16;
typedef __attribute__((ext_vector_type(8))) __bf16 bf16x8;
typedef __attribute__((ext_vector_type(4))) float f32x4;
typedef __attribute__((ext_vector_type(4))) unsigned short u16x4;
typedef __attribute__((ext_vector_type(8))) unsigned short u16x8;

__device__ __forceinline__ u16 f2bf(float f) {
  unsigned int u = __float_as_uint(f);
  u += 0x7FFFu + ((u >> 16) & 1u);  // RNE
  return (u16)(u >> 16);
}

__device__ __forceinline__ void gld_lds16(const void* g, void* l) {
  __builtin_amdgcn_global_load_lds((const __attribute__((address_space(1))) void*)g,
                                   (__attribute__((address_space(3))) void*)l, 16, 0, 0);
}

// Stage ROUNDS*32 rows x 64 bf16 into a swizzled LDS tile (row stride 128B,
// byte ^= (row&7)<<4). F32=1: f32 source, convert in reg, swizzled ds_write.
// F32=0: bf16 source, global_load_lds with source-preswizzled column (rule 21).
template <int F32, int ROUNDS>
__device__ __forceinline__ void stage_tile(const char* src, long long row0, long long ld,
                                           long long kb, u16* lds, int tid) {
#pragma unroll
  for (int r = 0; r < ROUNDS; ++r) {
    const int off = r * 4096 + tid * 16;
    const int row = off >> 7;
    const int colb = off & 127;
    if constexpr (F32) {
      const float* p = (const float*)src + (row0 + row) * ld + kb + (colb >> 1);
      f32x4 v0 = *(const f32x4*)p;
      f32x4 v1 = *(const f32x4*)(p + 4);
      u16x8 o;
      o[0] = f2bf(v0[0]); o[1] = f2bf(v0[1]); o[2] = f2bf(v0[2]); o[3] = f2bf(v0[3]);
      o[4] = f2bf(v1[0]); o[5] = f2bf(v1[1]); o[6] = f2bf(v1[2]); o[7] = f2bf(v1[3]);
      *(u16x8*)((char*)lds + (off ^ ((row & 7) << 4))) = o;
    } else {
      const int colb2 = colb ^ ((row & 7) << 4);
      const u16* p = (const u16*)src + (row0 + row) * ld + kb + (colb2 >> 1);
      gld_lds16(p, (char*)lds + off);
    }
  }
}

// One K=64 step of a 128x128 4-wave tile (A,B both 128B-stride swizzled LDS).
__device__ __forceinline__ void mfma_step(const u16* Alds, const u16* Blds, int lane, int wr,
                                          int wc, f32x4 (&acc)[4][4]) {
#pragma unroll
  for (int kk = 0; kk < 2; ++kk) {
    const int ko2 = (kk * 32 + (lane >> 4) * 8) * 2;
    bf16x8 a[4], b[4];
#pragma unroll
    for (int m = 0; m < 4; ++m) {
      const int ar = wr + m * 16 + (lane & 15);
      a[m] = *(const bf16x8*)((const char*)Alds + ((ar * 128 + ko2) ^ ((ar & 7) << 4)));
    }
#pragma unroll
    for (int n = 0; n < 4; ++n) {
      const int br = wc + n * 16 + (lane & 15);
      b[n] = *(const bf16x8*)((const char*)Blds + ((br * 128 + ko2) ^ ((br & 7) << 4)));
    }
#pragma unroll
    for (int m = 0; m < 4; ++m)
#pragma unroll
      for (int n = 0; n < 4; ++n)
        acc[m][n] = __builtin_amdgcn_mfma_f32_16x16x32_bf16(a[m], b[n], acc[m][n], 0, 0, 0);
  }
}

// K1: KV[b] = [Wk;Wv] @ I[b]^T. 1024 blocks, XCD-swizzled so the 4 M-tiles
// sharing one I-chunk run on the same XCD (mT fastest in logical id).
__global__ __launch_bounds__(256) void gemm_kv(const float* __restrict__ Wk,
                                               const float* __restrict__ Wv,
                                               const float* __restrict__ I,
                                               u16* __restrict__ KV) {
  __shared__ u16 Alds[8192];
  __shared__ u16 Blds[8192];
  const int tid = threadIdx.x;
  const int lane = tid & 63;
  const int w = tid >> 6;
  const int wr = (w >> 1) * 64, wc = (w & 1) * 64;
  const int l = ((blockIdx.x & 7) << 7) + (blockIdx.x >> 3);  // bijective, 1024 = 8*128
  const int mT = l & 3;
  const int nT = (l >> 2) & 63;
  const int b = l >> 8;
  const float* A = (mT < 2) ? (Wk + (long long)mT * 32768)
                            : (Wv + (long long)(mT - 2) * 32768);
  const float* B = I + (long long)b * 2097152 + (long long)nT * 32768;
  f32x4 acc[4][4];
#pragma unroll
  for (int m = 0; m < 4; ++m)
#pragma unroll
    for (int n = 0; n < 4; ++n) acc[m][n] = f32x4{0.f, 0.f, 0.f, 0.f};
  for (int kt = 0; kt < 4; ++kt) {
    __syncthreads();
    stage_tile<1, 4>((const char*)A, 0, 256, kt * 64, Alds, tid);
    stage_tile<1, 4>((const char*)B, 0, 256, kt * 64, Blds, tid);
    __syncthreads();
    mfma_step(Alds, Blds, lane, wr, wc, acc);
  }
  const int r0 = (lane >> 4) * 4, c0 = lane & 15;
  u16* Cb = KV + (long long)b * 4194304;
#pragma unroll
  for (int m = 0; m < 4; ++m)
#pragma unroll
    for (int n = 0; n < 4; ++n) {
      const int row = mT * 128 + wr + m * 16 + r0;
      const int col = nT * 128 + wc + n * 16 + c0;
#pragma unroll
      for (int j = 0; j < 4; ++j)
        Cb[(long long)(row + j) * 8192 + col] = f2bf(acc[m][n][j]);
    }
}

// K2: split-K partials for KeT (half 0) and VfT (half 1). 512 blocks.
__global__ __launch_bounds__(256) void gemm_k2(const float* __restrict__ We,
                                               const float* __restrict__ Wf,
                                               const u16* __restrict__ KV,
                                               float* __restrict__ Pp) {
  __shared__ u16 Alds[8192];
  __shared__ u16 Blds[8192];
  const int tid = threadIdx.x;
  const int lane = tid & 63;
  const int w = tid >> 6;
  const int wr = (w >> 1) * 64, wc = (w & 1) * 64;
  const int l = ((blockIdx.x & 7) << 6) + (blockIdx.x >> 3);  // bijective, 512 = 8*64
  const int mT = l & 1;
  const int nT = (l >> 1) & 1;
  const int zz = l >> 2;
  const int split = zz & 15;
  const int b = (zz >> 4) & 3;
  const int half = zz >> 6;
  f32x4 acc[4][4];
#pragma unroll
  for (int m = 0; m < 4; ++m)
#pragma unroll
    for (int n = 0; n < 4; ++n) acc[m][n] = f32x4{0.f, 0.f, 0.f, 0.f};
  const long long k00 = (long long)split * 512;
  if (half == 0) {  // KeT partial = We_chunk @ Kt_chunk^T
    const char* A = (const char*)We;
    const char* B = (const char*)(KV + (long long)b * 4194304);
    for (int kt = 0; kt < 8; ++kt) {
      __syncthreads();
      stage_tile<1, 4>(A, mT * 128, 8192, k00 + kt * 64, Alds, tid);
      stage_tile<0, 4>(B, nT * 128, 8192, k00 + kt * 64, Blds, tid);
      __syncthreads();
      mfma_step(Alds, Blds, lane, wr, wc, acc);
    }
  } else {  // VfT partial = Vt_chunk @ Wf_chunk^T
    const char* A = (const char*)(KV + (long long)b * 4194304 + 2097152);
    const char* B = (const char*)Wf;
    for (int kt = 0; kt < 8; ++kt) {
      __syncthreads();
      stage_tile<0, 4>(A, mT * 128, 8192, k00 + kt * 64, Alds, tid);
      stage_tile<1, 4>(B, nT * 128, 8192, k00 + kt * 64, Blds, tid);
      __syncthreads();
      mfma_step(Alds, Blds, lane, wr, wc, acc);
    }
  }
  const int r0 = (lane >> 4) * 4, c0 = lane & 15;
  float* Cb = Pp + ((long long)(half * 4 + b) * 16 + split) * 65536;
#pragma unroll
  for (int m = 0; m < 4; ++m)
#pragma unroll
    for (int n = 0; n < 4; ++n) {
      const int row = mT * 128 + wr + m * 16 + r0;
      const int col = nT * 128 + wc + n * 16 + c0;
#pragma unroll
      for (int j = 0; j < 4; ++j) Cb[(row + j) * 256 + col] = acc[m][n][j];
    }
}

// K3: sum 16 split-K partials -> bf16. P: [8][16][65536] f32, O: [8][65536] bf16.
__global__ __launch_bounds__(256) void reduce16(const float* __restrict__ P,
                                                u16* __restrict__ O) {
  const long long t = (long long)blockIdx.x * 256 + threadIdx.x;  // [0, 131072)
  const long long g = t >> 14;
  const long long e = (t & 16383) << 2;
  const float* p = P + g * 1048576 + e;
  f32x4 s = {0.f, 0.f, 0.f, 0.f};
#pragma unroll
  for (int i = 0; i < 16; ++i) s += *(const f32x4*)(p + i * 65536);
  u16x4 o = {f2bf(s[0]), f2bf(s[1]), f2bf(s[2]), f2bf(s[3])};
  *(u16x4*)(O + g * 65536 + e) = o;
}

// K4: per 64-row block: Q = I@Wq^T -> S = Q@KeT^T -> softmax -> Head = P@VfT^T.
// 4 waves; each wave owns a 64x64 output quadrant column slice (4x4 frags).
__global__ __launch_bounds__(256, 2) void flash2(const float* __restrict__ I,
                                                 const float* __restrict__ Wq,
                                                 const u16* __restrict__ KeT,
                                                 const u16* __restrict__ VfT,
                                                 float* __restrict__ out) {
  __shared__ u16 As[4096];    // 64 x 64 (I chunk)
  __shared__ u16 Bs[16384];   // 256 x 64 (Wq / KeT / VfT chunk)
  __shared__ u16 Qs[16384];   // 64 x 256, row stride 512B, swizzled (Q, then P)
  __shared__ float Ms[256];   // [row][wave] partial max
  __shared__ float Ss[256];   // [row][wave] partial sum
  const int tid = threadIdx.x;
  const int lane = tid & 63;
  const int w = tid >> 6;
  const int wc = w * 64;
  const int l = ((blockIdx.x & 7) << 6) + (blockIdx.x >> 3);  // XCD swizzle, 512 = 8*64
  const long long R0 = (long long)l * 64;
  const int batch = (int)(R0 >> 13);
  const u16* KeTb = KeT + (long long)batch * 65536;
  const u16* VfTb = VfT + (long long)batch * 65536;
  const int r0 = (lane >> 4) * 4, c0 = lane & 15;

  f32x4 acc[4][4];
#pragma unroll
  for (int m = 0; m < 4; ++m)
#pragma unroll
    for (int n = 0; n < 4; ++n) acc[m][n] = f32x4{0.f, 0.f, 0.f, 0.f};

  // ---- Phase A: Q = I_blk @ Wq^T ----
  for (int dc = 0; dc < 4; ++dc) {
    __syncthreads();
    stage_tile<1, 2>((const char*)I, R0, 256, dc * 64, As, tid);
    stage_tile<1, 8>((const char*)Wq, 0, 256, dc * 64, Bs, tid);
    __syncthreads();
    mfma_step(As, Bs, lane, 0, wc, acc);
  }
  // Q -> Qs (bf16), wave w owns cols [wc, wc+64)
#pragma unroll
  for (int m = 0; m < 4; ++m)
#pragma unroll
    for (int n = 0; n < 4; ++n) {
      const int col = wc + n * 16 + c0;
#pragma unroll
      for (int j = 0; j < 4; ++j) {
        const int row = m * 16 + r0 + j;
        *(u16*)((char*)Qs + ((row * 512 + col * 2) ^ ((row & 7) << 4))) = f2bf(acc[m][n][j]);
      }
    }
#pragma unroll
  for (int m = 0; m < 4; ++m)
#pragma unroll
    for (int n = 0; n < 4; ++n) acc[m][n] = f32x4{0.f, 0.f, 0.f, 0.f};

  // ---- Phase B: S = Q @ KeT^T (wave w -> k cols [wc, wc+64)) ----
  for (int kc = 0; kc < 4; ++kc) {
    __syncthreads();  // also orders Qs writes vs cross-wave reads
    stage_tile<0, 8>((const char*)KeTb, 0, 256, kc * 64, Bs, tid);
    __syncthreads();
#pragma unroll
    for (int kk = 0; kk < 2; ++kk) {
      const int ko = kk * 32 + (lane >> 4) * 8;
      bf16x8 a[4], b[4];
#pragma unroll
      for (int m = 0; m < 4; ++m) {
        const int ar = m * 16 + (lane & 15);
        a[m] = *(const bf16x8*)((const char*)Qs +
                                ((ar * 512 + (kc * 64 + ko) * 2) ^ ((ar & 7) << 4)));
      }
#pragma unroll
      for (int n = 0; n < 4; ++n) {
        const int br = wc + n * 16 + (lane & 15);
        b[n] = *(const bf16x8*)((const char*)Bs + ((br * 128 + ko * 2) ^ ((br & 7) << 4)));
      }
#pragma unroll
      for (int m = 0; m < 4; ++m)
#pragma unroll
        for (int n = 0; n < 4; ++n)
          acc[m][n] = __builtin_amdgcn_mfma_f32_16x16x32_bf16(a[m], b[n], acc[m][n], 0, 0, 0);
    }
  }

  // ---- softmax over k=256 (cols split across 4 waves) ----
  float red[4][4];
#pragma unroll
  for (int m = 0; m < 4; ++m)
#pragma unroll
    for (int j = 0; j < 4; ++j)
      red[m][j] = fmaxf(fmaxf(acc[m][0][j], acc[m][1][j]), fmaxf(acc[m][2][j], acc[m][3][j]));
#pragma unroll
  for (int d = 1; d < 16; d <<= 1)
#pragma unroll
    for (int m = 0; m < 4; ++m)
#pragma unroll
      for (int j = 0; j < 4; ++j) red[m][j] = fmaxf(red[m][j], __shfl_xor(red[m][j], d));
  if ((lane & 15) == 0) {
#pragma unroll
    for (int m = 0; m < 4; ++m)
#pragma unroll
      for (int j = 0; j < 4; ++j) Ms[(m * 16 + r0 + j) * 4 + w] = red[m][j];
  }
  __syncthreads();  // all waves done with Phase B + Ms visible
  float gm[4][4];
#pragma unroll
  for (int m = 0; m < 4; ++m)
#pragma unroll
    for (int j = 0; j < 4; ++j) {
      const f32x4 t = *(const f32x4*)&Ms[(m * 16 + r0 + j) * 4];
      gm[m][j] = fmaxf(fmaxf(t[0], t[1]), fmaxf(t[2], t[3]));
    }
#pragma unroll
  for (int m = 0; m < 4; ++m)
#pragma unroll
    for (int j = 0; j < 4; ++j) {
      float s = 0.f;
#pragma unroll
      for (int n = 0; n < 4; ++n) {
        const float e = __expf((acc[m][n][j] - gm[m][j]) * 0.0625f);
        acc[m][n][j] = e;
        s += e;
      }
      red[m][j] = s;
    }
#pragma unroll
  for (int d = 1; d < 16; d <<= 1)
#pragma unroll
    for (int m = 0; m < 4; ++m)
#pragma unroll
      for (int j = 0; j < 4; ++j) red[m][j] += __shfl_xor(red[m][j], d);
  if ((lane & 15) == 0) {
#pragma unroll
    for (int m = 0; m < 4; ++m)
#pragma unroll
      for (int j = 0; j < 4; ++j) Ss[(m * 16 + r0 + j) * 4 + w] = red[m][j];
  }
  __syncthreads();
  // P -> Qs (bf16, scaled by 1/sum)
#pragma unroll
  for (int m = 0; m < 4; ++m)
#pragma unroll
    for (int j = 0; j < 4; ++j) {
      const int row = m * 16 + r0 + j;
      const f32x4 t = *(const f32x4*)&Ss[row * 4];
      const float inv = 1.0f / (t[0] + t[1] + t[2] + t[3]);
#pragma unroll
      for (int n = 0; n < 4; ++n) {
        const int col = wc + n * 16 + c0;
        *(u16*)((char*)Qs + ((row * 512 + col * 2) ^ ((row & 7) << 4))) =
            f2bf(acc[m][n][j] * inv);
      }
    }
#pragma unroll
  for (int m = 0; m < 4; ++m)
#pragma unroll
    for (int n = 0; n < 4; ++n) acc[m][n] = f32x4{0.f, 0.f, 0.f, 0.f};

  // ---- Phase C: Head = P @ VfT^T (wave w -> d cols [wc, wc+64)) ----
  for (int kc = 0; kc < 4; ++kc) {
    __syncthreads();  // orders P writes vs cross-wave reads + Bs WAR
    stage_tile<0, 8>((const char*)VfTb, 0, 256, kc * 64, Bs, tid);
    __syncthreads();
#pragma unroll
    for (int kk = 0; kk < 2; ++kk) {
      const int ko = kk * 32 + (lane >> 4) * 8;
      bf16x8 a[4], b[4];
#pragma unroll
      for (int m = 0; m < 4; ++m) {
        const int ar = m * 16 + (lane & 15);
        a[m] = *(const bf16x8*)((const char*)Qs +
                                ((ar * 512 + (kc * 64 + ko) * 2) ^ ((ar & 7) << 4)));
      }
#pragma unroll
      for (int n = 0; n < 4; ++n) {
        const int br = wc + n * 16 + (lane & 15);
        b[n] = *(const bf16x8*)((const char*)Bs + ((br * 128 + ko * 2) ^ ((br & 7) << 4)));
      }
#pragma unroll
      for (int m = 0; m < 4; ++m)
#pragma unroll
        for (int n = 0; n < 4; ++n)
          acc[m][n] = __builtin_amdgcn_mfma_f32_16x16x32_bf16(a[m], b[n], acc[m][n], 0, 0, 0);
    }
  }

  // ---- store f32 out ----
#pragma unroll
  for (int m = 0; m < 4; ++m)
#pragma unroll
    for (int n = 0; n < 4; ++n) {
      const long long row = R0 + m * 16 + r0;
      const int col = wc + n * 16 + c0;
#pragma unroll
      for (int j = 0; j < 4; ++j) out[(row + j) * 256 + col] = acc[m][n][j];
    }
}

extern "C" void kernel_launch(void* const* d_in, const int* in_sizes, int n_in, void* d_out,
                              int out_size, void* d_ws, size_t ws_size, hipStream_t stream) {
  (void)in_sizes; (void)n_in; (void)out_size; (void)ws_size;
  const float* I  = (const float*)d_in[0];
  const float* Wq = (const float*)d_in[1];
  const float* Wk = (const float*)d_in[2];
  const float* Wv = (const float*)d_in[3];
  const float* We = (const float*)d_in[4];
  const float* Wf = (const float*)d_in[5];
  float* out = (float*)d_out;
  char* ws = (char*)d_ws;

  u16* KVp  = (u16*)ws;                      // 33.5 MB [4][512][8192] bf16
  float* Pp = (float*)(ws + 33554432);       // 33.5 MB [8][16][65536] f32
  u16* KeTp = (u16*)(ws + 67108864);         // 1 MB    [8][65536] bf16
  u16* VfTp = KeTp + 262144;

  gemm_kv<<<1024, 256, 0, stream>>>(Wk, Wv, I, KVp);
  gemm_k2<<<512, 256, 0, stream>>>(We, Wf, KVp, Pp);
  reduce16<<<512, 256, 0, stream>>>(Pp, KeTp);
  flash2<<<512, 256, 0, stream>>>(I, Wq, KeTp, VfTp, out);
}

// Round 4
// 190.412 us; speedup vs baseline: 1.1837x; 1.1837x over previous
//
#include <hip/hip_runtime.h>
#include <stdint.h>

// Linformer attention, MI355X gfx950 — 4-dispatch pipeline.
//  K1 (1664 blk): per 128-row I-chunk on one XCD: 4 KV-blocks ([Wk;Wv]@I^T) + 2 Q-blocks
//                 (I@Wq^T); + 128 blocks converting We/Wf -> bf16.
//  K2 (256 blk):  {KeT,VfT} split-K=8 partials, all-bf16 staging.
//  K3 (512 blk):  reduce 8 partials -> KeT/VfT bf16.
//  K4 (512 blk):  flash3: S=Q@KeT^T -> softmax -> P(LDS) -> Head=P@VfT^T -> f32 out.

typedef unsigned short u16;
typedef __attribute__((ext_vector_type(8))) __bf16 bf16x8;
typedef __attribute__((ext_vector_type(4))) float f32x4;
typedef __attribute__((ext_vector_type(4))) unsigned short u16x4;
typedef __attribute__((ext_vector_type(8))) unsigned short u16x8;

__device__ __forceinline__ u16 f2bf(float f) {
  unsigned int u = __float_as_uint(f);
  u += 0x7FFFu + ((u >> 16) & 1u);  // RNE
  return (u16)(u >> 16);
}

__device__ __forceinline__ void gld_lds16(const void* g, void* l) {
  __builtin_amdgcn_global_load_lds((const __attribute__((address_space(1))) void*)g,
                                   (__attribute__((address_space(3))) void*)l, 16, 0, 0);
}

// Stage ROUNDS*32 rows x 64 bf16 into swizzled LDS tile (row stride 128B,
// byte ^= (row&7)<<4). F32=1: f32 src, convert, swizzled ds_write.
// F32=0: bf16 src, global_load_lds with source-preswizzled column (rule 21).
template <int F32, int ROUNDS>
__device__ __forceinline__ void stage_tile(const char* src, long long row0, long long ld,
                                           long long kb, u16* lds, int tid) {
#pragma unroll
  for (int r = 0; r < ROUNDS; ++r) {
    const int off = r * 4096 + tid * 16;
    const int row = off >> 7;
    const int colb = off & 127;
    if constexpr (F32) {
      const float* p = (const float*)src + (row0 + row) * ld + kb + (colb >> 1);
      f32x4 v0 = *(const f32x4*)p;
      f32x4 v1 = *(const f32x4*)(p + 4);
      u16x8 o;
      o[0] = f2bf(v0[0]); o[1] = f2bf(v0[1]); o[2] = f2bf(v0[2]); o[3] = f2bf(v0[3]);
      o[4] = f2bf(v1[0]); o[5] = f2bf(v1[1]); o[6] = f2bf(v1[2]); o[7] = f2bf(v1[3]);
      *(u16x8*)((char*)lds + (off ^ ((row & 7) << 4))) = o;
    } else {
      const int colb2 = colb ^ ((row & 7) << 4);
      const u16* p = (const u16*)src + (row0 + row) * ld + kb + (colb2 >> 1);
      gld_lds16(p, (char*)lds + off);
    }
  }
}

// One K=64 step of a 128x128 4-wave tile (A,B both 128B-stride swizzled LDS).
__device__ __forceinline__ void mfma_step(const u16* Alds, const u16* Blds, int lane, int wr,
                                          int wc, f32x4 (&acc)[4][4]) {
#pragma unroll
  for (int kk = 0; kk < 2; ++kk) {
    const int ko2 = (kk * 32 + (lane >> 4) * 8) * 2;
    bf16x8 a[4], b[4];
#pragma unroll
    for (int m = 0; m < 4; ++m) {
      const int ar = wr + m * 16 + (lane & 15);
      a[m] = *(const bf16x8*)((const char*)Alds + ((ar * 128 + ko2) ^ ((ar & 7) << 4)));
    }
#pragma unroll
    for (int n = 0; n < 4; ++n) {
      const int br = wc + n * 16 + (lane & 15);
      b[n] = *(const bf16x8*)((const char*)Blds + ((br * 128 + ko2) ^ ((br & 7) << 4)));
    }
#pragma unroll
    for (int m = 0; m < 4; ++m)
#pragma unroll
      for (int n = 0; n < 4; ++n)
        acc[m][n] = __builtin_amdgcn_mfma_f32_16x16x32_bf16(a[m], b[n], acc[m][n], 0, 0, 0);
  }
}

// K1: fused projections + weight conversion.
// p in [0,1536): GEMM blocks. chunk = I 128-row chunk, 6 sub-blocks per chunk
// co-located on one XCD: sub 0-3 = KV rows (Wk/Wv halves), sub 4-5 = Q col-halves.
// p in [1536,1664): convert We (64 blk) / Wf (64 blk) f32 -> bf16.
__global__ __launch_bounds__(256) void k1(const float* __restrict__ I,
                                          const float* __restrict__ Wq,
                                          const float* __restrict__ Wk,
                                          const float* __restrict__ Wv,
                                          const float* __restrict__ We,
                                          const float* __restrict__ Wf,
                                          u16* __restrict__ KV, u16* __restrict__ Qb,
                                          u16* __restrict__ WB) {
  const int p = blockIdx.x;
  const int tid = threadIdx.x;
  if (p >= 1536) {
    const int q = p - 1536;
    const float* sB = ((q < 64) ? We : Wf) + (long long)(q & 63) * 32768;
    u16* dB = WB + (long long)(q >> 6) * 2097152 + (long long)(q & 63) * 32768;
#pragma unroll
    for (int r = 0; r < 16; ++r) {
      const int e = (r * 256 + tid) * 8;
      f32x4 v0 = *(const f32x4*)(sB + e);
      f32x4 v1 = *(const f32x4*)(sB + e + 4);
      u16x8 o;
      o[0] = f2bf(v0[0]); o[1] = f2bf(v0[1]); o[2] = f2bf(v0[2]); o[3] = f2bf(v0[3]);
      o[4] = f2bf(v1[0]); o[5] = f2bf(v1[1]); o[6] = f2bf(v1[2]); o[7] = f2bf(v1[3]);
      *(u16x8*)(dB + e) = o;
    }
    return;
  }
  __shared__ u16 Alds[8192];
  __shared__ u16 Blds[8192];
  const int xcd = p & 7;
  const int slot = p >> 3;
  const int chunk = ((slot / 6) << 3) | xcd;  // [0,256)
  const int sub = slot % 6;
  const int lane = tid & 63;
  const int w = tid >> 6;
  const int wr = (w >> 1) * 64, wc = (w & 1) * 64;

  const float* Asrc;
  const float* Bsrc;
  long long arow, brow, crow, ccol, ldc;
  u16* C;
  if (sub < 4) {  // KV: C[b][sub*128+i][nT*128+j] = W_kv @ I[b]^T
    Asrc = (sub < 2) ? Wk : Wv;
    arow = (long long)(sub & 1) * 128;
    Bsrc = I + (long long)(chunk >> 6) * 2097152;
    brow = (long long)(chunk & 63) * 128;
    C = KV + (long long)(chunk >> 6) * 4194304;
    crow = (long long)sub * 128;
    ccol = (long long)(chunk & 63) * 128;
    ldc = 8192;
  } else {  // Q: C[chunk*128+i][dT*128+j] = I @ Wq^T
    Asrc = I;
    arow = (long long)chunk * 128;
    Bsrc = Wq;
    brow = (long long)(sub - 4) * 128;
    C = Qb;
    crow = (long long)chunk * 128;
    ccol = (long long)(sub - 4) * 128;
    ldc = 256;
  }

  f32x4 acc[4][4];
#pragma unroll
  for (int m = 0; m < 4; ++m)
#pragma unroll
    for (int n = 0; n < 4; ++n) acc[m][n] = f32x4{0.f, 0.f, 0.f, 0.f};

  for (int kt = 0; kt < 4; ++kt) {
    __syncthreads();
    stage_tile<1, 4>((const char*)Asrc, arow, 256, kt * 64, Alds, tid);
    stage_tile<1, 4>((const char*)Bsrc, brow, 256, kt * 64, Blds, tid);
    __syncthreads();
    mfma_step(Alds, Blds, lane, wr, wc, acc);
  }

  const int r0 = (lane >> 4) * 4, c0 = lane & 15;
#pragma unroll
  for (int m = 0; m < 4; ++m)
#pragma unroll
    for (int n = 0; n < 4; ++n) {
      const long long row = crow + wr + m * 16 + r0;
      const long long col = ccol + wc + n * 16 + c0;
#pragma unroll
      for (int j = 0; j < 4; ++j) C[(row + j) * ldc + col] = f2bf(acc[m][n][j]);
    }
}

// K2: split-K=8 partials for KeT (half 0: We_bf @ Kt^T) and VfT (half 1: Vt @ Wf_bf^T).
__global__ __launch_bounds__(256) void gemm_k2(const u16* __restrict__ WB,
                                               const u16* __restrict__ KV,
                                               float* __restrict__ Pp) {
  __shared__ u16 Alds[8192];
  __shared__ u16 Blds[8192];
  const int tid = threadIdx.x;
  const int lane = tid & 63;
  const int w = tid >> 6;
  const int wr = (w >> 1) * 64, wc = (w & 1) * 64;
  const int l = ((blockIdx.x & 7) << 5) + (blockIdx.x >> 3);  // bijective, 256 = 8*32
  const int mT = l & 1;
  const int nT = (l >> 1) & 1;
  const int split = (l >> 2) & 7;
  const int b = (l >> 5) & 3;
  const int half = l >> 7;
  const u16 *A, *B;
  if (half == 0) {
    A = WB;                                          // We_bf [256][8192]
    B = KV + (long long)b * 4194304;                 // Kt [256][8192]
  } else {
    A = KV + (long long)b * 4194304 + 2097152;       // Vt [256][8192]
    B = WB + 2097152;                                // Wf_bf [256][8192]
  }
  const long long arow = (long long)mT * 128;
  const long long brow = (long long)nT * 128;
  const long long k00 = (long long)split * 1024;

  f32x4 acc[4][4];
#pragma unroll
  for (int m = 0; m < 4; ++m)
#pragma unroll
    for (int n = 0; n < 4; ++n) acc[m][n] = f32x4{0.f, 0.f, 0.f, 0.f};

  for (int kt = 0; kt < 16; ++kt) {
    __syncthreads();
    stage_tile<0, 4>((const char*)A, arow, 8192, k00 + kt * 64, Alds, tid);
    stage_tile<0, 4>((const char*)B, brow, 8192, k00 + kt * 64, Blds, tid);
    __syncthreads();
    mfma_step(Alds, Blds, lane, wr, wc, acc);
  }

  const int r0 = (lane >> 4) * 4, c0 = lane & 15;
  float* Cb = Pp + ((long long)(half * 4 + b) * 8 + split) * 65536;
#pragma unroll
  for (int m = 0; m < 4; ++m)
#pragma unroll
    for (int n = 0; n < 4; ++n) {
      const int row = (int)arow + wr + m * 16 + r0;
      const int col = (int)brow + wc + n * 16 + c0;
#pragma unroll
      for (int j = 0; j < 4; ++j) Cb[(row + j) * 256 + col] = acc[m][n][j];
    }
}

// K3: sum 8 split-K partials -> bf16. P: [8][8][65536] f32, O: [8][65536] bf16.
__global__ __launch_bounds__(256) void reduce8(const float* __restrict__ P,
                                               u16* __restrict__ O) {
  const long long t = (long long)blockIdx.x * 256 + threadIdx.x;  // [0, 131072)
  const long long g = t >> 14;
  const long long e = (t & 16383) << 2;
  const float* p = P + g * 524288 + e;
  f32x4 s = {0.f, 0.f, 0.f, 0.f};
#pragma unroll
  for (int i = 0; i < 8; ++i) s += *(const f32x4*)(p + i * 65536);
  u16x4 o = {f2bf(s[0]), f2bf(s[1]), f2bf(s[2]), f2bf(s[3])};
  *(u16x4*)(O + g * 65536 + e) = o;
}

// Stage a 256x64 bf16 tile (src row stride 256) into Bs, source-preswizzled.
__device__ __forceinline__ void stage_bs(const u16* src, u16* Bs, int tid) {
#pragma unroll
  for (int r = 0; r < 8; ++r) {
    const int off = r * 4096 + tid * 16;
    const int row = off >> 7;
    const int colb = (off & 127) ^ ((row & 7) << 4);
    gld_lds16(src + row * 256 + (colb >> 1), (char*)Bs + off);
  }
}

// K4: per 64-row block: S = Q@KeT^T -> softmax -> P(LDS) -> Head = P@VfT^T.
// 4 waves; wave w owns output cols [w*64, w*64+64) (4x4 frags).
__global__ __launch_bounds__(256) void flash3(const u16* __restrict__ Q,
                                              const u16* __restrict__ KeT,
                                              const u16* __restrict__ VfT,
                                              float* __restrict__ out) {
  __shared__ u16 Qs[16384];   // 64 x 256, row stride 512B, swizzled (Q, then P)
  __shared__ u16 Bs[16384];   // 256 x 64 (KeT / VfT chunk)
  __shared__ float Ms[256];   // [row][wave] partial max
  __shared__ float Ss[256];   // [row][wave] partial sum
  const int tid = threadIdx.x;
  const int lane = tid & 63;
  const int w = tid >> 6;
  const int wc = w * 64;
  const int l = ((blockIdx.x & 7) << 6) + (blockIdx.x >> 3);  // XCD swizzle, 512 = 8*64
  const long long R0 = (long long)l * 64;
  const int batch = (int)(R0 >> 13);
  const u16* KeTb = KeT + (long long)batch * 65536;
  const u16* VfTb = VfT + (long long)batch * 65536;
  const int r0 = (lane >> 4) * 4, c0 = lane & 15;

  // stage Q rows [R0, R0+64) x 256 into Qs (swizzled via source col)
#pragma unroll
  for (int r = 0; r < 8; ++r) {
    const int off = r * 4096 + tid * 16;
    const int row = off >> 9;
    const int colb = (off & 511) ^ ((row & 7) << 4);
    gld_lds16(Q + (R0 + row) * 256 + (colb >> 1), (char*)Qs + off);
  }

  f32x4 acc[4][4];
#pragma unroll
  for (int m = 0; m < 4; ++m)
#pragma unroll
    for (int n = 0; n < 4; ++n) acc[m][n] = f32x4{0.f, 0.f, 0.f, 0.f};

  // ---- Phase B: S = Q @ KeT^T (wave w -> k cols [wc, wc+64)) ----
  for (int kc = 0; kc < 4; ++kc) {
    __syncthreads();  // Bs WAR
    stage_bs(KeTb + kc * 64, Bs, tid);
    __syncthreads();  // drains vmcnt: Bs (and, at kc=0, Qs) ready
#pragma unroll
    for (int kk = 0; kk < 2; ++kk) {
      const int ko = kk * 32 + (lane >> 4) * 8;
      bf16x8 a[4], b[4];
#pragma unroll
      for (int m = 0; m < 4; ++m) {
        const int ar = m * 16 + (lane & 15);
        a[m] = *(const bf16x8*)((const char*)Qs +
                                ((ar * 512 + (kc * 64 + ko) * 2) ^ ((ar & 7) << 4)));
      }
#pragma unroll
      for (int n = 0; n < 4; ++n) {
        const int br = wc + n * 16 + (lane & 15);
        b[n] = *(const bf16x8*)((const char*)Bs + ((br * 128 + ko * 2) ^ ((br & 7) << 4)));
      }
#pragma unroll
      for (int m = 0; m < 4; ++m)
#pragma unroll
        for (int n = 0; n < 4; ++n)
          acc[m][n] = __builtin_amdgcn_mfma_f32_16x16x32_bf16(a[m], b[n], acc[m][n], 0, 0, 0);
    }
  }

  // ---- softmax over k=256 (cols split across 4 waves) ----
  float red[4][4];
#pragma unroll
  for (int m = 0; m < 4; ++m)
#pragma unroll
    for (int j = 0; j < 4; ++j)
      red[m][j] = fmaxf(fmaxf(acc[m][0][j], acc[m][1][j]), fmaxf(acc[m][2][j], acc[m][3][j]));
#pragma unroll
  for (int d = 1; d < 16; d <<= 1)
#pragma unroll
    for (int m = 0; m < 4; ++m)
#pragma unroll
      for (int j = 0; j < 4; ++j) red[m][j] = fmaxf(red[m][j], __shfl_xor(red[m][j], d));
  if ((lane & 15) == 0) {
#pragma unroll
    for (int m = 0; m < 4; ++m)
#pragma unroll
      for (int j = 0; j < 4; ++j) Ms[(m * 16 + r0 + j) * 4 + w] = red[m][j];
  }
  __syncthreads();
  float gm[4][4];
#pragma unroll
  for (int m = 0; m < 4; ++m)
#pragma unroll
    for (int j = 0; j < 4; ++j) {
      const f32x4 t = *(const f32x4*)&Ms[(m * 16 + r0 + j) * 4];
      gm[m][j] = fmaxf(fmaxf(t[0], t[1]), fmaxf(t[2], t[3]));
    }
#pragma unroll
  for (int m = 0; m < 4; ++m)
#pragma unroll
    for (int j = 0; j < 4; ++j) {
      float s = 0.f;
#pragma unroll
      for (int n = 0; n < 4; ++n) {
        const float e = __expf((acc[m][n][j] - gm[m][j]) * 0.0625f);
        acc[m][n][j] = e;
        s += e;
      }
      red[m][j] = s;
    }
#pragma unroll
  for (int d = 1; d < 16; d <<= 1)
#pragma unroll
    for (int m = 0; m < 4; ++m)
#pragma unroll
      for (int j = 0; j < 4; ++j) red[m][j] += __shfl_xor(red[m][j], d);
  if ((lane & 15) == 0) {
#pragma unroll
    for (int m = 0; m < 4; ++m)
#pragma unroll
      for (int j = 0; j < 4; ++j) Ss[(m * 16 + r0 + j) * 4 + w] = red[m][j];
  }
  __syncthreads();  // also: all waves past Phase B reads of Qs
  // P -> Qs (bf16, scaled by 1/sum)
#pragma unroll
  for (int m = 0; m < 4; ++m)
#pragma unroll
    for (int j = 0; j < 4; ++j) {
      const int row = m * 16 + r0 + j;
      const f32x4 t = *(const f32x4*)&Ss[row * 4];
      const float inv = 1.0f / (t[0] + t[1] + t[2] + t[3]);
#pragma unroll
      for (int n = 0; n < 4; ++n) {
        const int col = wc + n * 16 + c0;
        *(u16*)((char*)Qs + ((row * 512 + col * 2) ^ ((row & 7) << 4))) =
            f2bf(acc[m][n][j] * inv);
      }
    }
#pragma unroll
  for (int m = 0; m < 4; ++m)
#pragma unroll
    for (int n = 0; n < 4; ++n) acc[m][n] = f32x4{0.f, 0.f, 0.f, 0.f};

  // ---- Phase C: Head = P @ VfT^T (wave w -> d cols [wc, wc+64)) ----
  for (int kc = 0; kc < 4; ++kc) {
    __syncthreads();  // P writes visible + Bs WAR
    stage_bs(VfTb + kc * 64, Bs, tid);
    __syncthreads();
#pragma unroll
    for (int kk = 0; kk < 2; ++kk) {
      const int ko = kk * 32 + (lane >> 4) * 8;
      bf16x8 a[4], b[4];
#pragma unroll
      for (int m = 0; m < 4; ++m) {
        const int ar = m * 16 + (lane & 15);
        a[m] = *(const bf16x8*)((const char*)Qs +
                                ((ar * 512 + (kc * 64 + ko) * 2) ^ ((ar & 7) << 4)));
      }
#pragma unroll
      for (int n = 0; n < 4; ++n) {
        const int br = wc + n * 16 + (lane & 15);
        b[n] = *(const bf16x8*)((const char*)Bs + ((br * 128 + ko * 2) ^ ((br & 7) << 4)));
      }
#pragma unroll
      for (int m = 0; m < 4; ++m)
#pragma unroll
        for (int n = 0; n < 4; ++n)
          acc[m][n] = __builtin_amdgcn_mfma_f32_16x16x32_bf16(a[m], b[n], acc[m][n], 0, 0, 0);
    }
  }

  // ---- store f32 out ----
#pragma unroll
  for (int m = 0; m < 4; ++m)
#pragma unroll
    for (int n = 0; n < 4; ++n) {
      const long long row = R0 + m * 16 + r0;
      const int col = wc + n * 16 + c0;
#pragma unroll
      for (int j = 0; j < 4; ++j) out[(row + j) * 256 + col] = acc[m][n][j];
    }
}

extern "C" void kernel_launch(void* const* d_in, const int* in_sizes, int n_in, void* d_out,
                              int out_size, void* d_ws, size_t ws_size, hipStream_t stream) {
  (void)in_sizes; (void)n_in; (void)out_size; (void)ws_size;
  const float* I  = (const float*)d_in[0];
  const float* Wq = (const float*)d_in[1];
  const float* Wk = (const float*)d_in[2];
  const float* Wv = (const float*)d_in[3];
  const float* We = (const float*)d_in[4];
  const float* Wf = (const float*)d_in[5];
  float* out = (float*)d_out;
  char* ws = (char*)d_ws;

  u16* KVp   = (u16*)ws;                      // 33.5 MB [4][512][8192] bf16
  u16* Qbf   = (u16*)(ws + 33554432);         // 16.8 MB [32768][256] bf16
  u16* WBp   = (u16*)(ws + 50331648);         //  8.4 MB We_bf, Wf_bf
  float* Pp  = (float*)(ws + 58720256);       // 16.8 MB [8][8][65536] f32
  u16* KeTp  = (u16*)(ws + 75497472);         //  1 MB   [8][65536] bf16
  u16* VfTp  = KeTp + 262144;

  k1<<<1664, 256, 0, stream>>>(I, Wq, Wk, Wv, We, Wf, KVp, Qbf, WBp);
  gemm_k2<<<256, 256, 0, stream>>>(WBp, KVp, Pp);
  reduce8<<<512, 256, 0, stream>>>(Pp, KeTp);
  flash3<<<512, 256, 0, stream>>>(Qbf, KeTp, VfTp, out);
}

// Round 7
// 171.021 us; speedup vs baseline: 1.3179x; 1.1134x over previous
//
#include <hip/hip_runtime.h>
#include <stdint.h>

// Linformer attention, MI355X gfx950 — 5-dispatch, KV/Q tensors algebraically eliminated.
//  Identities: KeT[b] = (We@I[b]) @ Wk^T = Se@Wk^T ; VfT[b] = Wv @ (Wf@I[b])^T = Wv@Sf^T
//              logits = I @ Me^T with Me = Se @ G^T, G = Wq^T @ Wk
//  K0: convert I->Ibf + IT (transpose), WqT, WkT, Wv/We/Wf -> bf16
//  K1: Se/Sf split-K=16 partials (512 blk) + G (4 blk)
//  K2: reduce16 -> SS = [Se(4b); Sf(4b)] bf16
//  K3: Me = Se@G^T, VfT = Wv@Sf^T (32 blk)
//  K4: flash: logits = Ibf@Me^T -> softmax -> P(LDS) -> Head = P@VfT^T -> f32 out

typedef unsigned short u16;
typedef __attribute__((ext_vector_type(8))) __bf16 bf16x8;
typedef __attribute__((ext_vector_type(4))) float f32x4;
typedef __attribute__((ext_vector_type(4))) unsigned short u16x4;
typedef __attribute__((ext_vector_type(8))) unsigned short u16x8;

__device__ __forceinline__ u16 f2bf(float f) {
  unsigned int u = __float_as_uint(f);
  u += 0x7FFFu + ((u >> 16) & 1u);  // RNE
  return (u16)(u >> 16);
}

__device__ __forceinline__ void gld_lds16(const void* g, void* l) {
  __builtin_amdgcn_global_load_lds((const __attribute__((address_space(1))) void*)g,
                                   (__attribute__((address_space(3))) void*)l, 16, 0, 0);
}

// Stage 128 rows x 64 bf16 into swizzled LDS tile (row stride 128B, byte ^= (row&7)<<4),
// bf16 source via global_load_lds with source-preswizzled column (rule 21).
__device__ __forceinline__ void stage_tile(const u16* src, long long ld, long long kb,
                                           u16* lds, int tid) {
#pragma unroll
  for (int r = 0; r < 4; ++r) {
    const int off = r * 4096 + tid * 16;
    const int row = off >> 7;
    const int colb = (off & 127) ^ ((row & 7) << 4);
    gld_lds16(src + (long long)row * ld + kb + (colb >> 1), (char*)lds + off);
  }
}

// One K=64 step of a 128x128 4-wave tile (A,B both 128B-stride swizzled LDS).
__device__ __forceinline__ void mfma_step(const u16* Alds, const u16* Blds, int lane, int wr,
                                          int wc, f32x4 (&acc)[4][4]) {
#pragma unroll
  for (int kk = 0; kk < 2; ++kk) {
    const int ko2 = (kk * 32 + (lane >> 4) * 8) * 2;
    bf16x8 a[4], b[4];
#pragma unroll
    for (int m = 0; m < 4; ++m) {
      const int ar = wr + m * 16 + (lane & 15);
      a[m] = *(const bf16x8*)((const char*)Alds + ((ar * 128 + ko2) ^ ((ar & 7) << 4)));
    }
#pragma unroll
    for (int n = 0; n < 4; ++n) {
      const int br = wc + n * 16 + (lane & 15);
      b[n] = *(const bf16x8*)((const char*)Blds + ((br * 128 + ko2) ^ ((br & 7) << 4)));
    }
#pragma unroll
    for (int m = 0; m < 4; ++m)
#pragma unroll
      for (int n = 0; n < 4; ++n)
        acc[m][n] = __builtin_amdgcn_mfma_f32_16x16x32_bf16(a[m], b[n], acc[m][n], 0, 0, 0);
  }
}

// K0: conversions + transposes.
//  [0,2048): I 64x64 tiles -> Ibf (straight) + IT (transposed)
//  [2048,2080): Wq (16) / Wk (16) 64x64 tiles -> WqT / WkT (transposed only)
//  [2080,3120): straight converts Wv|We|Wf (4096 elems/block)
__global__ __launch_bounds__(256) void k0(const float* __restrict__ I,
                                          const float* __restrict__ Wq,
                                          const float* __restrict__ Wk,
                                          const float* __restrict__ Wv,
                                          const float* __restrict__ We,
                                          const float* __restrict__ Wf,
                                          u16* __restrict__ Ibf, u16* __restrict__ IT,
                                          u16* __restrict__ WqT, u16* __restrict__ WkT,
                                          u16* __restrict__ WvB, u16* __restrict__ WeB,
                                          u16* __restrict__ WfB) {
  const int p = blockIdx.x, t = threadIdx.x;
  if (p < 2080) {
    __shared__ u16 T[4096];  // 64x64, micro-permuted for conflict-light transpose
    const float* src;
    u16 *dT, *dS;
    long long srow, scol, tld;
    if (p < 2048) {
      const int b = p >> 9, id = p & 511;
      src = I + (long long)b * 2097152;
      srow = (long long)(id >> 2) * 64;
      scol = (long long)(id & 3) * 64;
      dS = Ibf + (long long)b * 2097152;
      dT = IT + (long long)b * 2097152;
      tld = 8192;
    } else {
      const int q = p - 2048;
      src = (q < 16) ? Wq : Wk;
      const int id = q & 15;
      srow = (long long)(id >> 2) * 64;
      scol = (long long)(id & 3) * 64;
      dS = nullptr;
      dT = (q < 16) ? WqT : WkT;
      tld = 256;
    }
    const int cc = t & 15, rL = t >> 4;
#pragma unroll
    for (int i = 0; i < 4; ++i) {
      const int r = rL + 16 * i;
      f32x4 v = *(const f32x4*)(src + (srow + r) * 256 + scol + cc * 4);
      u16x4 o = {f2bf(v[0]), f2bf(v[1]), f2bf(v[2]), f2bf(v[3])};
      if (dS) *(u16x4*)(dS + (srow + r) * 256 + scol + cc * 4) = o;
      const int P = (cc + (r & 15) + 4 * (r >> 4)) & 15;  // element (r,c) at T[r*64+P*4+(c&3)]
      *(u16x4*)&T[r * 64 + P * 4] = o;
    }
    __syncthreads();
    const int dd = t >> 2, ch2 = t & 3;
    u16 buf[16];
#pragma unroll
    for (int j = 0; j < 16; ++j) {
      const int P = ((dd >> 2) + j + 4 * ch2) & 15;  // rr = ch2*16+j: rr&15=j, rr>>4=ch2
      buf[j] = T[(ch2 * 16 + j) * 64 + P * 4 + (dd & 3)];
    }
    u16* dp = dT + (scol + dd) * tld + srow + ch2 * 16;
    *(u16x8*)dp = *(u16x8*)&buf[0];
    *(u16x8*)(dp + 8) = *(u16x8*)&buf[8];
  } else {
    const long long base = (long long)(p - 2080) * 4096;
#pragma unroll
    for (int rnd = 0; rnd < 4; ++rnd) {
      const long long e = base + rnd * 1024 + t * 4;
      const float* s;
      u16* d;
      long long eo;
      if (e < 65536) { s = Wv; d = WvB; eo = e; }
      else if (e < 2162688) { s = We; d = WeB; eo = e - 65536; }
      else { s = Wf; d = WfB; eo = e - 2162688; }
      f32x4 v = *(const f32x4*)(s + eo);
      *(u16x4*)(d + eo) = u16x4{f2bf(v[0]), f2bf(v[1]), f2bf(v[2]), f2bf(v[3])};
    }
  }
}

// K1: blocks [0,512): Se/Sf split-K=16 partials; [512,516): G = WqT @ WkT^T.
__global__ __launch_bounds__(256) void k1(const u16* __restrict__ WqT,
                                          const u16* __restrict__ WkT,
                                          const u16* __restrict__ WeB,
                                          const u16* __restrict__ WfB,
                                          const u16* __restrict__ IT,
                                          float* __restrict__ Pp, u16* __restrict__ G) {
  __shared__ u16 Alds[8192];
  __shared__ u16 Blds[8192];
  const int tid = threadIdx.x, lane = tid & 63, w = tid >> 6;
  const int wr = (w >> 1) * 64, wc = (w & 1) * 64;
  const u16 *A, *Bp;
  long long lda, k0, crow, ccol;
  int nkt;
  float* Cf = nullptr;
  u16* Cb = nullptr;
  if (blockIdx.x >= 512) {
    const int tl = blockIdx.x - 512;
    crow = (long long)(tl >> 1) * 128;
    ccol = (long long)(tl & 1) * 128;
    A = WqT + crow * 256;
    Bp = WkT + ccol * 256;
    lda = 256; k0 = 0; nkt = 4;
    Cb = G;
  } else {
    const int l = ((blockIdx.x & 7) << 6) + (blockIdx.x >> 3);  // bijective, 512 = 8*64
    const int mT = l & 1, nT = (l >> 1) & 1, s = (l >> 2) & 15, b = (l >> 6) & 3, op = l >> 8;
    A = (op ? WfB : WeB) + (long long)mT * 128 * 8192;
    Bp = IT + (long long)b * 2097152 + (long long)nT * 128 * 8192;
    lda = 8192;
    k0 = (long long)s * 512;
    nkt = 8;
    Cf = Pp + ((long long)(op * 4 + b) * 16 + s) * 65536;
    crow = (long long)mT * 128;
    ccol = (long long)nT * 128;
  }

  f32x4 acc[4][4];
#pragma unroll
  for (int m = 0; m < 4; ++m)
#pragma unroll
    for (int n = 0; n < 4; ++n) acc[m][n] = f32x4{0.f, 0.f, 0.f, 0.f};

  for (int kt = 0; kt < nkt; ++kt) {
    __syncthreads();
    stage_tile(A, lda, k0 + kt * 64, Alds, tid);
    stage_tile(Bp, lda, k0 + kt * 64, Blds, tid);
    __syncthreads();
    mfma_step(Alds, Blds, lane, wr, wc, acc);
  }

  const int r0 = (lane >> 4) * 4, c0 = lane & 15;
#pragma unroll
  for (int m = 0; m < 4; ++m)
#pragma unroll
    for (int n = 0; n < 4; ++n) {
      const long long row = crow + wr + m * 16 + r0;
      const long long col = ccol + wc + n * 16 + c0;
#pragma unroll
      for (int j = 0; j < 4; ++j) {
        if (Cf) Cf[(row + j) * 256 + col] = acc[m][n][j];
        else Cb[(row + j) * 256 + col] = f2bf(acc[m][n][j]);
      }
    }
}

// K2: sum 16 split-K partials -> bf16. Pp: [8][16][65536] f32, SS: [8][65536] bf16.
__global__ __launch_bounds__(256) void reduce16(const float* __restrict__ P,
                                                u16* __restrict__ O) {
  const long long t = (long long)blockIdx.x * 256 + threadIdx.x;  // [0, 131072)
  const long long g = t >> 14;
  const long long e = (t & 16383) << 2;
  const float* p = P + g * 1048576 + e;
  f32x4 s = {0.f, 0.f, 0.f, 0.f};
#pragma unroll
  for (int i = 0; i < 16; ++i) s += *(const f32x4*)(p + i * 65536);
  u16x4 o = {f2bf(s[0]), f2bf(s[1]), f2bf(s[2]), f2bf(s[3])};
  *(u16x4*)(O + g * 65536 + e) = o;
}

// K3: 32 blocks: [0,16): Me[b] = Se[b]@G^T ; [16,32): VfT[b] = Wv@Sf[b]^T.
__global__ __launch_bounds__(256) void k3(const u16* __restrict__ SS, const u16* __restrict__ G,
                                          const u16* __restrict__ WvB, u16* __restrict__ Me,
                                          u16* __restrict__ VfT) {
  __shared__ u16 Alds[8192];
  __shared__ u16 Blds[8192];
  const int tid = threadIdx.x, lane = tid & 63, w = tid >> 6;
  const int wr = (w >> 1) * 64, wc = (w & 1) * 64;
  const int u = blockIdx.x;
  const int path = u >> 4, b = (u >> 2) & 3, mT = (u >> 1) & 1, nT = u & 1;
  const u16 *A, *Bp;
  u16* C;
  if (path == 0) { A = SS + b * 65536; Bp = G; C = Me + b * 65536; }
  else { A = WvB; Bp = SS + (4 + b) * 65536; C = VfT + b * 65536; }
  A += (long long)mT * 128 * 256;
  Bp += (long long)nT * 128 * 256;

  f32x4 acc[4][4];
#pragma unroll
  for (int m = 0; m < 4; ++m)
#pragma unroll
    for (int n = 0; n < 4; ++n) acc[m][n] = f32x4{0.f, 0.f, 0.f, 0.f};

  for (int kt = 0; kt < 4; ++kt) {
    __syncthreads();
    stage_tile(A, 256, kt * 64, Alds, tid);
    stage_tile(Bp, 256, kt * 64, Blds, tid);
    __syncthreads();
    mfma_step(Alds, Blds, lane, wr, wc, acc);
  }

  const int r0 = (lane >> 4) * 4, c0 = lane & 15;
#pragma unroll
  for (int m = 0; m < 4; ++m)
#pragma unroll
    for (int n = 0; n < 4; ++n) {
      const int row = mT * 128 + wr + m * 16 + r0;
      const int col = nT * 128 + wc + n * 16 + c0;
#pragma unroll
      for (int j = 0; j < 4; ++j) C[(row + j) * 256 + col] = f2bf(acc[m][n][j]);
    }
}

// Stage a 256x64 bf16 tile (src row stride 256) into Bs, source-preswizzled.
__device__ __forceinline__ void stage_bs(const u16* src, u16* Bs, int tid) {
#pragma unroll
  for (int r = 0; r < 8; ++r) {
    const int off = r * 4096 + tid * 16;
    const int row = off >> 7;
    const int colb = (off & 127) ^ ((row & 7) << 4);
    gld_lds16(src + row * 256 + (colb >> 1), (char*)Bs + off);
  }
}

// K4: per 64-row block: S = Ibf@Me^T -> softmax -> P(LDS) -> Head = P@VfT^T.
__global__ __launch_bounds__(256) void flash3(const u16* __restrict__ Q,
                                              const u16* __restrict__ KeT,
                                              const u16* __restrict__ VfT,
                                              float* __restrict__ out) {
  __shared__ u16 Qs[16384];   // 64 x 256, row stride 512B, swizzled (I rows, then P)
  __shared__ u16 Bs[16384];   // 256 x 64 (Me / VfT chunk)
  __shared__ float Ms[256];
  __shared__ float Ss[256];
  const int tid = threadIdx.x;
  const int lane = tid & 63;
  const int w = tid >> 6;
  const int wc = w * 64;
  const int l = ((blockIdx.x & 7) << 6) + (blockIdx.x >> 3);  // XCD swizzle, 512 = 8*64
  const long long R0 = (long long)l * 64;
  const int batch = (int)(R0 >> 13);
  const u16* KeTb = KeT + (long long)batch * 65536;
  const u16* VfTb = VfT + (long long)batch * 65536;
  const int r0 = (lane >> 4) * 4, c0 = lane & 15;

#pragma unroll
  for (int r = 0; r < 8; ++r) {
    const int off = r * 4096 + tid * 16;
    const int row = off >> 9;
    const int colb = (off & 511) ^ ((row & 7) << 4);
    gld_lds16(Q + (R0 + row) * 256 + (colb >> 1), (char*)Qs + off);
  }

  f32x4 acc[4][4];
#pragma unroll
  for (int m = 0; m < 4; ++m)
#pragma unroll
    for (int n = 0; n < 4; ++n) acc[m][n] = f32x4{0.f, 0.f, 0.f, 0.f};

  // ---- Phase B: S = I @ Me^T (wave w -> k cols [wc, wc+64)) ----
  for (int kc = 0; kc < 4; ++kc) {
    __syncthreads();
    stage_bs(KeTb + kc * 64, Bs, tid);
    __syncthreads();
#pragma unroll
    for (int kk = 0; kk < 2; ++kk) {
      const int ko = kk * 32 + (lane >> 4) * 8;
      bf16x8 a[4], b[4];
#pragma unroll
      for (int m = 0; m < 4; ++m) {
        const int ar = m * 16 + (lane & 15);
        a[m] = *(const bf16x8*)((const char*)Qs +
                                ((ar * 512 + (kc * 64 + ko) * 2) ^ ((ar & 7) << 4)));
      }
#pragma unroll
      for (int n = 0; n < 4; ++n) {
        const int br = wc + n * 16 + (lane & 15);
        b[n] = *(const bf16x8*)((const char*)Bs + ((br * 128 + ko * 2) ^ ((br & 7) << 4)));
      }
#pragma unroll
      for (int m = 0; m < 4; ++m)
#pragma unroll
        for (int n = 0; n < 4; ++n)
          acc[m][n] = __builtin_amdgcn_mfma_f32_16x16x32_bf16(a[m], b[n], acc[m][n], 0, 0, 0);
    }
  }

  // ---- softmax over k=256 (cols split across 4 waves) ----
  float red[4][4];
#pragma unroll
  for (int m = 0; m < 4; ++m)
#pragma unroll
    for (int j = 0; j < 4; ++j)
      red[m][j] = fmaxf(fmaxf(acc[m][0][j], acc[m][1][j]), fmaxf(acc[m][2][j], acc[m][3][j]));
#pragma unroll
  for (int d = 1; d < 16; d <<= 1)
#pragma unroll
    for (int m = 0; m < 4; ++m)
#pragma unroll
      for (int j = 0; j < 4; ++j) red[m][j] = fmaxf(red[m][j], __shfl_xor(red[m][j], d));
  if ((lane & 15) == 0) {
#pragma unroll
    for (int m = 0; m < 4; ++m)
#pragma unroll
      for (int j = 0; j < 4; ++j) Ms[(m * 16 + r0 + j) * 4 + w] = red[m][j];
  }
  __syncthreads();
  float gm[4][4];
#pragma unroll
  for (int m = 0; m < 4; ++m)
#pragma unroll
    for (int j = 0; j < 4; ++j) {
      const f32x4 t = *(const f32x4*)&Ms[(m * 16 + r0 + j) * 4];
      gm[m][j] = fmaxf(fmaxf(t[0], t[1]), fmaxf(t[2], t[3]));
    }
#pragma unroll
  for (int m = 0; m < 4; ++m)
#pragma unroll
    for (int j = 0; j < 4; ++j) {
      float s = 0.f;
#pragma unroll
      for (int n = 0; n < 4; ++n) {
        const float e = __expf((acc[m][n][j] - gm[m][j]) * 0.0625f);
        acc[m][n][j] = e;
        s += e;
      }
      red[m][j] = s;
    }
#pragma unroll
  for (int d = 1; d < 16; d <<= 1)
#pragma unroll
    for (int m = 0; m < 4; ++m)
#pragma unroll
      for (int j = 0; j < 4; ++j) red[m][j] += __shfl_xor(red[m][j], d);
  if ((lane & 15) == 0) {
#pragma unroll
    for (int m = 0; m < 4; ++m)
#pragma unroll
      for (int j = 0; j < 4; ++j) Ss[(m * 16 + r0 + j) * 4 + w] = red[m][j];
  }
  __syncthreads();
#pragma unroll
  for (int m = 0; m < 4; ++m)
#pragma unroll
    for (int j = 0; j < 4; ++j) {
      const int row = m * 16 + r0 + j;
      const f32x4 t = *(const f32x4*)&Ss[row * 4];
      const float inv = 1.0f / (t[0] + t[1] + t[2] + t[3]);
#pragma unroll
      for (int n = 0; n < 4; ++n) {
        const int col = wc + n * 16 + c0;
        *(u16*)((char*)Qs + ((row * 512 + col * 2) ^ ((row & 7) << 4))) =
            f2bf(acc[m][n][j] * inv);
      }
    }
#pragma unroll
  for (int m = 0; m < 4; ++m)
#pragma unroll
    for (int n = 0; n < 4; ++n) acc[m][n] = f32x4{0.f, 0.f, 0.f, 0.f};

  // ---- Phase C: Head = P @ VfT^T ----
  for (int kc = 0; kc < 4; ++kc) {
    __syncthreads();
    stage_bs(VfTb + kc * 64, Bs, tid);
    __syncthreads();
#pragma unroll
    for (int kk = 0; kk < 2; ++kk) {
      const int ko = kk * 32 + (lane >> 4) * 8;
      bf16x8 a[4], b[4];
#pragma unroll
      for (int m = 0; m < 4; ++m) {
        const int ar = m * 16 + (lane & 15);
        a[m] = *(const bf16x8*)((const char*)Qs +
                                ((ar * 512 + (kc * 64 + ko) * 2) ^ ((ar & 7) << 4)));
      }
#pragma unroll
      for (int n = 0; n < 4; ++n) {
        const int br = wc + n * 16 + (lane & 15);
        b[n] = *(const bf16x8*)((const char*)Bs + ((br * 128 + ko * 2) ^ ((br & 7) << 4)));
      }
#pragma unroll
      for (int m = 0; m < 4; ++m)
#pragma unroll
        for (int n = 0; n < 4; ++n)
          acc[m][n] = __builtin_amdgcn_mfma_f32_16x16x32_bf16(a[m], b[n], acc[m][n], 0, 0, 0);
    }
  }

#pragma unroll
  for (int m = 0; m < 4; ++m)
#pragma unroll
    for (int n = 0; n < 4; ++n) {
      const long long row = R0 + m * 16 + r0;
      const int col = wc + n * 16 + c0;
#pragma unroll
      for (int j = 0; j < 4; ++j) out[(row + j) * 256 + col] = acc[m][n][j];
    }
}

extern "C" void kernel_launch(void* const* d_in, const int* in_sizes, int n_in, void* d_out,
                              int out_size, void* d_ws, size_t ws_size, hipStream_t stream) {
  (void)in_sizes; (void)n_in; (void)out_size; (void)ws_size;
  const float* I  = (const float*)d_in[0];
  const float* Wq = (const float*)d_in[1];
  const float* Wk = (const float*)d_in[2];
  const float* Wv = (const float*)d_in[3];
  const float* We = (const float*)d_in[4];
  const float* Wf = (const float*)d_in[5];
  float* out = (float*)d_out;
  char* ws = (char*)d_ws;

  u16* Ibf  = (u16*)(ws + 0);          // 16.8 MB [32768][256]
  u16* IT   = (u16*)(ws + 16777216);   // 16.8 MB [4][256][8192]
  u16* WqT  = (u16*)(ws + 33554432);   // 128 KB (transposed)
  u16* WkT  = (u16*)(ws + 33685504);   // 128 KB (transposed)
  u16* WvB  = (u16*)(ws + 33816576);   // 128 KB
  u16* WeB  = (u16*)(ws + 33947648);   // 4 MB
  u16* WfB  = (u16*)(ws + 38141952);   // 4 MB
  u16* G    = (u16*)(ws + 42336256);   // 128 KB
  float* Pp = (float*)(ws + 42467328); // 33.5 MB [8][16][65536]
  u16* SS   = (u16*)(ws + 76021760);   // 1 MB [8][65536] (Se b0..3, Sf b0..3)
  u16* Me   = (u16*)(ws + 77070336);   // 512 KB [4][256][256]
  u16* VfT  = (u16*)(ws + 77594624);   // 512 KB [4][256][256]

  k0<<<3120, 256, 0, stream>>>(I, Wq, Wk, Wv, We, Wf, Ibf, IT, WqT, WkT, WvB, WeB, WfB);
  k1<<<516, 256, 0, stream>>>(WqT, WkT, WeB, WfB, IT, Pp, G);
  reduce16<<<512, 256, 0, stream>>>(Pp, SS);
  k3<<<32, 256, 0, stream>>>(SS, G, WvB, Me, VfT);
  flash3<<<512, 256, 0, stream>>>(Ibf, Me, VfT, out);
}